// Round 11
// baseline (265.216 us; speedup 1.0000x reference)
//
#include <hip/hip_runtime.h>
#include <cmath>

typedef __attribute__((ext_vector_type(8))) short bf16x8;
typedef __attribute__((ext_vector_type(4))) float f32x4;

// ---------- bf16 pack/unpack ----------
static __device__ __forceinline__ unsigned short f2bf(float f) {
    unsigned u = __float_as_uint(f);
    unsigned r = (u + 0x7fffu + ((u >> 16) & 1u)) >> 16;   // RNE
    return (unsigned short)r;
}
static __device__ __forceinline__ unsigned packbf(float a, float b) {
    return (unsigned)f2bf(a) | ((unsigned)f2bf(b) << 16);
}
static __device__ __forceinline__ float bflo(unsigned u) { return __uint_as_float(u << 16); }
static __device__ __forceinline__ float bfhi(unsigned u) { return __uint_as_float(u & 0xffff0000u); }

#define SCAN_BLK 256
#define SCAN_ELEMS 2048

// ---------- fused prep: x->bf16, W transposes->bf16, edge count, chain zero ----------
__global__ void prep_k(const float* __restrict__ x, const float* __restrict__ W1,
                       const float* __restrict__ W2, const int* __restrict__ dst,
                       unsigned* __restrict__ xb,
                       unsigned short* __restrict__ Wt1, unsigned short* __restrict__ Wt2,
                       int* __restrict__ deg, int* __restrict__ chain,
                       int NX2, int NW1, int NW2, int E, int NCH) {
    int i = blockIdx.x * blockDim.x + threadIdx.x;
    if (i < NX2) {
        float2 v = reinterpret_cast<const float2*>(x)[i];
        xb[i] = packbf(v.x, v.y);
        return;
    }
    i -= NX2;
    if (i < NW1) { int nn = i / 128, k = i % 128; Wt1[i] = f2bf(W1[(size_t)k * 256 + nn]); return; }
    i -= NW1;
    if (i < NW2) { int nn = i / 256, k = i % 256; Wt2[i] = f2bf(W2[(size_t)k * 128 + nn]); return; }
    i -= NW2;
    if (i < E) { atomicAdd(&deg[dst[i]], 1); return; }
    i -= E;
    if (i < NCH) chain[i] = 0;
}

// ---------- single-kernel CSR scan (chained block prefixes) ----------
// deg[i]+1 (implicit self-loop); finalizes rowstart, self-loop adj, cursor.
// cursor aliases deg (disjoint per-block slices: read-before-write within block).
__global__ void csr_build_k(const int* __restrict__ deg, int* __restrict__ rowstart,
                            int* __restrict__ adj, int* __restrict__ cursor,
                            int* __restrict__ chain, int N, int total) {
    __shared__ int sh[SCAN_BLK];
    __shared__ int s_prefix;
    int t = threadIdx.x, b = blockIdx.x;
    int base = b * SCAN_ELEMS + t * 8;
    int vals[8];
    int sum = 0;
#pragma unroll
    for (int i = 0; i < 8; ++i) {
        int idx = base + i;
        vals[i] = (idx < N) ? (deg[idx] + 1) : 0;
        sum += vals[i];
    }
    sh[t] = sum;
    __syncthreads();
    for (int off = 1; off < SCAN_BLK; off <<= 1) {
        int v = (t >= off) ? sh[t - off] : 0;
        __syncthreads();
        sh[t] += v;
        __syncthreads();
    }
    int run = sh[t] - sum;              // exclusive prefix within block
    int blocksum = sh[SCAN_BLK - 1];
    if (t == 0) {
        int prev = 0;
        if (b > 0) {
            int c;
            while ((c = __hip_atomic_load(&chain[b], __ATOMIC_ACQUIRE, __HIP_MEMORY_SCOPE_AGENT)) == 0) {}
            prev = c - 1;
        }
        __hip_atomic_store(&chain[b + 1], prev + blocksum + 1, __ATOMIC_RELEASE, __HIP_MEMORY_SCOPE_AGENT);
        s_prefix = prev;
    }
    __syncthreads();
    int r = run + s_prefix;
#pragma unroll
    for (int i = 0; i < 8; ++i) {
        int idx = base + i;
        if (idx < N) {
            rowstart[idx] = r;
            adj[r] = idx;            // self-loop first
            cursor[idx] = r + 1;
        }
        r += vals[i];
    }
    if (b == gridDim.x - 1 && t == SCAN_BLK - 1) rowstart[N] = total;
}

__global__ void scatter_k(const int* __restrict__ src, const int* __restrict__ dst, int E,
                          int* __restrict__ cursor, int* __restrict__ adj) {
    int e = blockIdx.x * blockDim.x + threadIdx.x;
    if (e >= E) return;
    int pos = atomicAdd(&cursor[dst[e]], 1);
    adj[pos] = src[e];
}

// ---------- MFMA GEMM + fused attention scores ----------
template<int K, int NOUT, int H, int C>
__global__ __launch_bounds__(256) void gemm_score_k(const unsigned* __restrict__ Ab,
                                                    const unsigned* __restrict__ Bt,
                                                    unsigned short* __restrict__ Yb,
                                                    const float* __restrict__ asrc,
                                                    const float* __restrict__ adst,
                                                    float* __restrict__ ssrc,
                                                    float* __restrict__ sdst, int N) {
    __shared__ unsigned short As[128 * 64];
    __shared__ unsigned short Bs[64 * 64];
    __shared__ float sred[2][2][128];   // [wc][src/dst][row]
    int tid = threadIdx.x;
    int lane = tid & 63, wid = tid >> 6;
    int wm = wid >> 1, wc = wid & 1;
    int m0 = blockIdx.x * 128;
    int n0 = blockIdx.y * 64;

    f32x4 acc[4][2] = {};

    for (int k0 = 0; k0 < K; k0 += 64) {
#pragma unroll
        for (int p = 0; p < 4; ++p) {
            int gl = p * 256 + tid;
            int row = gl >> 3, g = gl & 7;
            int grow = m0 + row; if (grow >= N) grow = N - 1;
            uint4 v = *reinterpret_cast<const uint4*>(Ab + (size_t)grow * (K / 2) + k0 / 2 + g * 4);
            *reinterpret_cast<uint4*>((char*)As + row * 128 + ((g ^ (row & 7)) << 4)) = v;
        }
#pragma unroll
        for (int p = 0; p < 2; ++p) {
            int gl = p * 256 + tid;
            int row = gl >> 3, g = gl & 7;
            uint4 v = *reinterpret_cast<const uint4*>(Bt + (size_t)(n0 + row) * (K / 2) + k0 / 2 + g * 4);
            *reinterpret_cast<uint4*>((char*)Bs + row * 128 + ((g ^ (row & 7)) << 4)) = v;
        }
        __syncthreads();

        bf16x8 bfrag[2][2];
#pragma unroll
        for (int kk = 0; kk < 2; ++kk)
#pragma unroll
            for (int no = 0; no < 2; ++no) {
                int row = wc * 32 + no * 16 + (lane & 15);
                int g = kk * 4 + (lane >> 4);
                bfrag[kk][no] = *reinterpret_cast<const bf16x8*>((char*)Bs + row * 128 + ((g ^ (row & 7)) << 4));
            }
#pragma unroll
        for (int mo = 0; mo < 4; ++mo) {
#pragma unroll
            for (int kk = 0; kk < 2; ++kk) {
                int row = wm * 64 + mo * 16 + (lane & 15);
                int g = kk * 4 + (lane >> 4);
                bf16x8 afrag = *reinterpret_cast<const bf16x8*>((char*)As + row * 128 + ((g ^ (row & 7)) << 4));
                acc[mo][0] = __builtin_amdgcn_mfma_f32_16x16x32_bf16(afrag, bfrag[kk][0], acc[mo][0], 0, 0, 0);
                acc[mo][1] = __builtin_amdgcn_mfma_f32_16x16x32_bf16(afrag, bfrag[kk][1], acc[mo][1], 0, 0, 0);
            }
        }
        __syncthreads();
    }

    // ---- Yb store ----
#pragma unroll
    for (int mo = 0; mo < 4; ++mo)
#pragma unroll
        for (int no = 0; no < 2; ++no) {
            int col = n0 + wc * 32 + no * 16 + (lane & 15);
            int rbase = m0 + wm * 64 + mo * 16 + (lane >> 4) * 4;
#pragma unroll
            for (int j = 0; j < 4; ++j) {
                int row = rbase + j;
                if (row < N) Yb[(size_t)row * NOUT + col] = f2bf(acc[mo][no][j]);
            }
        }

    // ---- fused score epilogue ----
    float cs0, cs1, cd0, cd1;
    {
        int c0 = n0 + wc * 32 + (lane & 15);
        cs0 = asrc[c0]; cd0 = adst[c0];
        cs1 = asrc[c0 + 16]; cd1 = adst[c0 + 16];
    }
#pragma unroll
    for (int mo = 0; mo < 4; ++mo) {
        float ps[4], pd[4];
#pragma unroll
        for (int j = 0; j < 4; ++j) {
            ps[j] = acc[mo][0][j] * cs0 + acc[mo][1][j] * cs1;
            pd[j] = acc[mo][0][j] * cd0 + acc[mo][1][j] * cd1;
        }
#pragma unroll
        for (int off = 8; off; off >>= 1)
#pragma unroll
            for (int j = 0; j < 4; ++j) {
                ps[j] += __shfl_xor(ps[j], off, 64);
                pd[j] += __shfl_xor(pd[j], off, 64);
            }
        if ((lane & 15) == 0) {
            int rl = wm * 64 + mo * 16 + (lane >> 4) * 4;
#pragma unroll
            for (int j = 0; j < 4; ++j) {
                sred[wc][0][rl + j] = ps[j];
                sred[wc][1][rl + j] = pd[j];
            }
        }
    }
    __syncthreads();
    if (tid < 128) {
        int grow = m0 + tid;
        if (grow < N) {
            float fs = sred[0][0][tid] + sred[1][0][tid];
            float fd = sred[0][1][tid] + sred[1][1][tid];
            if constexpr (C <= 64) {
                int hh = n0 / C;
                ssrc[(size_t)grow * H + hh] = fs;
                sdst[(size_t)grow * H + hh] = fd;
            } else {
                atomicAdd(&ssrc[grow], fs);
                atomicAdd(&sdst[grow], fd);
            }
        }
    }
}

// ---------- fused per-node softmax + bf16 gather-aggregate + epilogue ----------
// One GRP-lane group per node; softmax without max-subtract; unnormalized alpha
// in per-group LDS tables ([H][64] layout: conflict-free writes); 8-deep gather.
template<int H, int C, int GRP, bool ELU, bool OUT_BF16>
__global__ void node_agg_k(const int* __restrict__ rowstart, const int* __restrict__ adj,
                           const float* __restrict__ ssrc, const float* __restrict__ sdst,
                           const unsigned* __restrict__ hb, const float* __restrict__ bias,
                           void* __restrict__ outp, int N) {
    constexpr int HC = H * C;
    constexpr int ROW_U = HC / 2;           // packed uints per row
    constexpr int ULN = ROW_U / GRP;        // uints per lane (=4: 16B)
    constexpr int FPLn = ULN * 2;           // features per lane (=8)
    constexpr int NG = 64 / GRP;            // groups (nodes) per wave
    constexpr int NGB = 4 * NG;             // groups per block (4 waves)
    int lane = threadIdx.x & 63;
    int w = threadIdx.x >> 6;
    int g = lane / GRP, ln = lane % GRP;
    int gid = w * NG + g;
    int n = blockIdx.x * NGB + gid;
    if (n >= N) return;

    __shared__ int   s_tab[NGB][64];
    __shared__ float a_tab[NGB][H][64];     // [H][64]: stride-1 writes per lane

    int r0 = rowstart[n], r1 = rowstart[n + 1];
    int deg = r1 - r0;

    float sd[H];
#pragma unroll
    for (int h = 0; h < H; ++h) sd[h] = sdst[n * H + h];

    int hA = (ln * FPLn) / C;
    const unsigned* hbl = hb + ln * ULN;
    float acc[FPLn];
#pragma unroll
    for (int f = 0; f < FPLn; ++f) acc[f] = 0.f;
    float l[H];
#pragma unroll
    for (int h = 0; h < H; ++h) l[h] = 0.f;

    if (deg <= 64) {
        // ---- pass 1: strided chunks of GRP edges; fill (s, alpha) tables ----
        for (int base = 0; base < deg; base += GRP) {
            int idx = base + ln;
            bool on = idx < deg;
            int s = adj[r0 + (on ? idx : 0)];
            float v[H];
            if constexpr (H == 4) {
                float4 sv = reinterpret_cast<const float4*>(ssrc)[s];
                v[0] = sv.x; v[1] = sv.y; v[2] = sv.z; v[3] = sv.w;
            } else {
                v[0] = ssrc[s];
            }
#pragma unroll
            for (int h = 0; h < H; ++h) {
                float t = v[h] + sd[h];
                t = t > 0.f ? t : 0.2f * t;
                float av = on ? __expf(t) : 0.f;
                l[h] += av;
                if (on) a_tab[gid][h][idx] = av;
            }
            if (on) s_tab[gid][idx] = s;
        }
#pragma unroll
        for (int off = GRP / 2; off; off >>= 1)
#pragma unroll
            for (int h = 0; h < H; ++h) l[h] += __shfl_xor(l[h], off, 64);

        // ---- pass 2: table-driven gather, 8-deep unroll ----
        const float* atab = a_tab[gid][hA];
        int j = 0;
        for (; j + 7 < deg; j += 8) {
            int ss[8]; float aa[8]; uint4 uu[8];
#pragma unroll
            for (int q = 0; q < 8; ++q) { ss[q] = s_tab[gid][j + q]; aa[q] = atab[j + q]; }
#pragma unroll
            for (int q = 0; q < 8; ++q) uu[q] = *reinterpret_cast<const uint4*>(hbl + (size_t)ss[q] * ROW_U);
#pragma unroll
            for (int q = 0; q < 8; ++q) {
                acc[0] += aa[q] * bflo(uu[q].x); acc[1] += aa[q] * bfhi(uu[q].x);
                acc[2] += aa[q] * bflo(uu[q].y); acc[3] += aa[q] * bfhi(uu[q].y);
                acc[4] += aa[q] * bflo(uu[q].z); acc[5] += aa[q] * bfhi(uu[q].z);
                acc[6] += aa[q] * bflo(uu[q].w); acc[7] += aa[q] * bfhi(uu[q].w);
            }
        }
        for (; j + 1 < deg; j += 2) {
            int s0 = s_tab[gid][j], s1 = s_tab[gid][j + 1];
            float a0 = atab[j], a1 = atab[j + 1];
            uint4 u0 = *reinterpret_cast<const uint4*>(hbl + (size_t)s0 * ROW_U);
            uint4 u1 = *reinterpret_cast<const uint4*>(hbl + (size_t)s1 * ROW_U);
            acc[0] += a0 * bflo(u0.x); acc[1] += a0 * bfhi(u0.x);
            acc[2] += a0 * bflo(u0.y); acc[3] += a0 * bfhi(u0.y);
            acc[4] += a0 * bflo(u0.z); acc[5] += a0 * bfhi(u0.z);
            acc[6] += a0 * bflo(u0.w); acc[7] += a0 * bfhi(u0.w);
            acc[0] += a1 * bflo(u1.x); acc[1] += a1 * bfhi(u1.x);
            acc[2] += a1 * bflo(u1.y); acc[3] += a1 * bfhi(u1.y);
            acc[4] += a1 * bflo(u1.z); acc[5] += a1 * bfhi(u1.z);
            acc[6] += a1 * bflo(u1.w); acc[7] += a1 * bfhi(u1.w);
        }
        if (j < deg) {
            int sj = s_tab[gid][j];
            float al = atab[j];
            uint4 u = *reinterpret_cast<const uint4*>(hbl + (size_t)sj * ROW_U);
            acc[0] += al * bflo(u.x); acc[1] += al * bfhi(u.x);
            acc[2] += al * bflo(u.y); acc[3] += al * bfhi(u.y);
            acc[4] += al * bflo(u.z); acc[5] += al * bfhi(u.z);
            acc[6] += al * bflo(u.w); acc[7] += al * bfhi(u.w);
        }
    } else {
        // ---- general path (deg > 64): sum pre-pass, recompute alpha in pass 2 ----
        for (int e = r0 + ln; e < r1; e += GRP) {
            int s = adj[e];
#pragma unroll
            for (int h = 0; h < H; ++h) {
                float t = ssrc[s * H + h] + sd[h];
                t = t > 0.f ? t : 0.2f * t;
                l[h] += __expf(t);
            }
        }
#pragma unroll
        for (int off = GRP / 2; off; off >>= 1)
#pragma unroll
            for (int h = 0; h < H; ++h) l[h] += __shfl_xor(l[h], off, 64);
        float sdh = sd[hA];
        for (int e = r0; e < r1; ++e) {
            int s = adj[e];
            float t = ssrc[s * H + hA] + sdh;
            t = t > 0.f ? t : 0.2f * t;
            float al = __expf(t);
            uint4 u = *reinterpret_cast<const uint4*>(hbl + (size_t)s * ROW_U);
            acc[0] += al * bflo(u.x); acc[1] += al * bfhi(u.x);
            acc[2] += al * bflo(u.y); acc[3] += al * bfhi(u.y);
            acc[4] += al * bflo(u.z); acc[5] += al * bfhi(u.z);
            acc[6] += al * bflo(u.w); acc[7] += al * bfhi(u.w);
        }
    }

    // ---- epilogue: normalize, bias, activation, store ----
    float invl = __builtin_amdgcn_rcpf(l[hA]);
#pragma unroll
    for (int f = 0; f < FPLn; ++f) {
        float v = acc[f] * invl + bias[ln * FPLn + f];
        if (ELU) v = v > 0.f ? v : (__expf(v) - 1.f);
        acc[f] = v;
    }
    if constexpr (OUT_BF16) {
        unsigned* op = (unsigned*)outp + (size_t)n * ROW_U + ln * ULN;
        uint4 u = {packbf(acc[0], acc[1]), packbf(acc[2], acc[3]),
                   packbf(acc[4], acc[5]), packbf(acc[6], acc[7])};
        *reinterpret_cast<uint4*>(op) = u;
    } else {
        float* op = (float*)outp + (size_t)n * HC + ln * FPLn;
        *reinterpret_cast<float4*>(op) = make_float4(acc[0], acc[1], acc[2], acc[3]);
        *reinterpret_cast<float4*>(op + 4) = make_float4(acc[4], acc[5], acc[6], acc[7]);
    }
}

// ---------- launch ----------
extern "C" void kernel_launch(void* const* d_in, const int* in_sizes, int n_in,
                              void* d_out, int out_size, void* d_ws, size_t ws_size,
                              hipStream_t stream) {
    const float* x   = (const float*)d_in[0];
    const int*   ei  = (const int*)d_in[1];
    const float* W1  = (const float*)d_in[2];
    const float* as1 = (const float*)d_in[3];
    const float* ad1 = (const float*)d_in[4];
    const float* b1  = (const float*)d_in[5];
    const float* W2  = (const float*)d_in[6];
    const float* as2 = (const float*)d_in[7];
    const float* ad2 = (const float*)d_in[8];
    const float* b2  = (const float*)d_in[9];
    float* out = (float*)d_out;

    const int N  = in_sizes[0] / 128;   // 50000
    const int E  = in_sizes[1] / 2;     // 800000
    const int ET = E + N;
    const int* src = ei;
    const int* dst = ei + E;

    // workspace (4B units)
    unsigned* ws = (unsigned*)d_ws;
    unsigned* xb    = ws;                              // N*64  (x bf16)
    unsigned* h1b   = xb    + (size_t)N * 64;          // N*128
    unsigned* agg1b = h1b   + (size_t)N * 128;         // N*128
    unsigned* h2b   = agg1b + (size_t)N * 128;         // N*64
    unsigned* Wt1   = h2b   + (size_t)N * 64;          // 16384
    unsigned* Wt2   = Wt1   + 16384;                   // 16384
    float*    ssrc1 = (float*)(Wt2 + 16384);           // N*4
    float*    sdst1 = ssrc1 + (size_t)N * 4;           // N*4
    float*    ssrc2 = sdst1 + (size_t)N * 4;           // N
    float*    sdst2 = ssrc2 + N;                       // N
    int*      deg   = (int*)(sdst2 + N);               // N (reused as cursor)
    int*      rowst = deg + N;                         // N+1
    int*      chain = rowst + N + 1;                   // nscan+1
    int*      adj   = chain + 128;                     // ET

    const int B = 256;
    auto blocks = [](size_t n, int b) { return (int)((n + b - 1) / b); };
    const int nscan = (N + SCAN_ELEMS - 1) / SCAN_ELEMS;

    // ---- zero ssrc2/sdst2/deg in one shot (contiguous) + fused prep ----
    hipMemsetAsync(ssrc2, 0, (size_t)N * 3 * 4, stream);
    {
        int NX2 = N * 64, NW1 = 128 * 256, NW2 = 256 * 128;
        size_t tot = (size_t)NX2 + NW1 + NW2 + E + (nscan + 1);
        prep_k<<<blocks(tot, B), B, 0, stream>>>(x, W1, W2, dst, xb, (unsigned short*)Wt1,
                                                 (unsigned short*)Wt2, deg, chain,
                                                 NX2, NW1, NW2, E, nscan + 1);
    }

    // ---- CSR build (single chained-scan kernel + scatter) ----
    csr_build_k<<<nscan, SCAN_BLK, 0, stream>>>(deg, rowst, adj, deg, chain, N, ET);
    scatter_k<<<blocks(E, B), B, 0, stream>>>(src, dst, E, deg, adj);

    // ---- layer 1 (GEMM + fused scores) ----
    {
        dim3 g((N + 127) / 128, 256 / 64);
        gemm_score_k<128, 256, 4, 64><<<g, 256, 0, stream>>>(
            xb, (const unsigned*)Wt1, (unsigned short*)h1b, as1, ad1, ssrc1, sdst1, N);
    }
    node_agg_k<4, 64, 32, true, true><<<(N + 7) / 8, 256, 0, stream>>>(rowst, adj, ssrc1, sdst1, h1b, b1, agg1b, N);

    // ---- layer 2 (GEMM + fused scores via atomics) ----
    {
        dim3 g((N + 127) / 128, 128 / 64);
        gemm_score_k<256, 128, 1, 128><<<g, 256, 0, stream>>>(
            agg1b, (const unsigned*)Wt2, (unsigned short*)h2b, as2, ad2, ssrc2, sdst2, N);
    }
    node_agg_k<1, 128, 16, false, false><<<(N + 15) / 16, 256, 0, stream>>>(rowst, adj, ssrc2, sdst2, h2b, b2, out, N);
}

// Round 12
// 245.081 us; speedup vs baseline: 1.0822x; 1.0822x over previous
//
#include <hip/hip_runtime.h>
#include <cmath>

typedef __attribute__((ext_vector_type(8))) short bf16x8;
typedef __attribute__((ext_vector_type(4))) float f32x4;

// ---------- bf16 pack/unpack ----------
static __device__ __forceinline__ unsigned short f2bf(float f) {
    unsigned u = __float_as_uint(f);
    unsigned r = (u + 0x7fffu + ((u >> 16) & 1u)) >> 16;   // RNE
    return (unsigned short)r;
}
static __device__ __forceinline__ unsigned packbf(float a, float b) {
    return (unsigned)f2bf(a) | ((unsigned)f2bf(b) << 16);
}
static __device__ __forceinline__ float bflo(unsigned u) { return __uint_as_float(u << 16); }
static __device__ __forceinline__ float bfhi(unsigned u) { return __uint_as_float(u & 0xffff0000u); }

// ---------- fused prep: W1/W2 transpose->bf16, edge count ----------
__global__ void prep_k(const float* __restrict__ W1, const float* __restrict__ W2,
                       const int* __restrict__ dst,
                       unsigned short* __restrict__ Wt1, unsigned short* __restrict__ Wt2,
                       int* __restrict__ deg, int NW1, int NW2, int E) {
    int i = blockIdx.x * blockDim.x + threadIdx.x;
    if (i < NW1) { int nn = i / 128, k = i % 128; Wt1[i] = f2bf(W1[(size_t)k * 256 + nn]); return; }
    i -= NW1;
    if (i < NW2) { int nn = i / 256, k = i % 256; Wt2[i] = f2bf(W2[(size_t)k * 128 + nn]); return; }
    i -= NW2;
    if (i < E) atomicAdd(&deg[dst[i]], 1);
}

#define SCAN_BLK 256
#define SCAN_ELEMS 2048

// scan1: deg[i]+1 (implicit self-loop)
__global__ void scan1_k(const int* __restrict__ deg, int* __restrict__ rowstart,
                        int* __restrict__ bsums, int N) {
    __shared__ int sh[SCAN_BLK];
    int t = threadIdx.x;
    int base = blockIdx.x * SCAN_ELEMS + t * 8;
    int vals[8];
    int sum = 0;
#pragma unroll
    for (int i = 0; i < 8; ++i) {
        int idx = base + i;
        vals[i] = (idx < N) ? (deg[idx] + 1) : 0;
        sum += vals[i];
    }
    sh[t] = sum;
    __syncthreads();
    for (int off = 1; off < SCAN_BLK; off <<= 1) {
        int v = (t >= off) ? sh[t - off] : 0;
        __syncthreads();
        sh[t] += v;
        __syncthreads();
    }
    int run = sh[t] - sum;
    if (t == SCAN_BLK - 1) bsums[blockIdx.x] = sh[t];
#pragma unroll
    for (int i = 0; i < 8; ++i) {
        int idx = base + i;
        if (idx < N) rowstart[idx] = run;
        run += vals[i];
    }
}
// wave-parallel exclusive scan of block sums (nb <= 64)
__global__ void scan2_k(int* __restrict__ bsums, int nb) {
    int lane = threadIdx.x;
    int own = (lane < nb) ? bsums[lane] : 0;
    int v = own;
    for (int off = 1; off < 64; off <<= 1) {
        int t = __shfl_up(v, off, 64);
        if (lane >= off) v += t;
    }
    if (lane < nb) bsums[lane] = v - own;
}
// scan3 + initadj fused
__global__ void scan3_init_k(int* __restrict__ rowstart, const int* __restrict__ bsums,
                             int* __restrict__ adj, int* __restrict__ cursor, int N, int total) {
    int i = blockIdx.x * blockDim.x + threadIdx.x;
    if (i < N) {
        int r = rowstart[i] + bsums[i / SCAN_ELEMS];
        rowstart[i] = r;
        adj[r] = i;          // self-loop first
        cursor[i] = r + 1;
    } else if (i == N) {
        rowstart[N] = total;
    }
}
__global__ void scatter_k(const int* __restrict__ src, const int* __restrict__ dst, int E,
                          int* __restrict__ cursor, int* __restrict__ adj) {
    int e = blockIdx.x * blockDim.x + threadIdx.x;
    if (e >= E) return;
    int pos = atomicAdd(&cursor[dst[e]], 1);
    adj[pos] = src[e];
}

// ---------- MFMA GEMM + fused attention scores ----------
// AF32: A matrix is f32 in global (converted to bf16 during LDS staging).
template<int K, int NOUT, int H, int C, bool AF32>
__global__ __launch_bounds__(256) void gemm_score_k(const void* __restrict__ Abv,
                                                    const unsigned* __restrict__ Bt,
                                                    unsigned short* __restrict__ Yb,
                                                    const float* __restrict__ asrc,
                                                    const float* __restrict__ adst,
                                                    float* __restrict__ ssrc,
                                                    float* __restrict__ sdst, int N) {
    __shared__ unsigned short As[128 * 64];
    __shared__ unsigned short Bs[64 * 64];
    __shared__ float sred[2][2][128];   // [wc][src/dst][row]
    int tid = threadIdx.x;
    int lane = tid & 63, wid = tid >> 6;
    int wm = wid >> 1, wc = wid & 1;
    int m0 = blockIdx.x * 128;
    int n0 = blockIdx.y * 64;

    f32x4 acc[4][2] = {};

    for (int k0 = 0; k0 < K; k0 += 64) {
#pragma unroll
        for (int p = 0; p < 4; ++p) {
            int gl = p * 256 + tid;
            int row = gl >> 3, g = gl & 7;
            int grow = m0 + row; if (grow >= N) grow = N - 1;
            uint4 v;
            if constexpr (AF32) {
                const float* xp = (const float*)Abv + (size_t)grow * K + k0 + g * 8;
                float4 f0 = *reinterpret_cast<const float4*>(xp);
                float4 f1 = *reinterpret_cast<const float4*>(xp + 4);
                v.x = packbf(f0.x, f0.y); v.y = packbf(f0.z, f0.w);
                v.z = packbf(f1.x, f1.y); v.w = packbf(f1.z, f1.w);
            } else {
                v = *reinterpret_cast<const uint4*>((const unsigned*)Abv + (size_t)grow * (K / 2) + k0 / 2 + g * 4);
            }
            *reinterpret_cast<uint4*>((char*)As + row * 128 + ((g ^ (row & 7)) << 4)) = v;
        }
#pragma unroll
        for (int p = 0; p < 2; ++p) {
            int gl = p * 256 + tid;
            int row = gl >> 3, g = gl & 7;
            uint4 v = *reinterpret_cast<const uint4*>(Bt + (size_t)(n0 + row) * (K / 2) + k0 / 2 + g * 4);
            *reinterpret_cast<uint4*>((char*)Bs + row * 128 + ((g ^ (row & 7)) << 4)) = v;
        }
        __syncthreads();

        bf16x8 bfrag[2][2];
#pragma unroll
        for (int kk = 0; kk < 2; ++kk)
#pragma unroll
            for (int no = 0; no < 2; ++no) {
                int row = wc * 32 + no * 16 + (lane & 15);
                int g = kk * 4 + (lane >> 4);
                bfrag[kk][no] = *reinterpret_cast<const bf16x8*>((char*)Bs + row * 128 + ((g ^ (row & 7)) << 4));
            }
#pragma unroll
        for (int mo = 0; mo < 4; ++mo) {
#pragma unroll
            for (int kk = 0; kk < 2; ++kk) {
                int row = wm * 64 + mo * 16 + (lane & 15);
                int g = kk * 4 + (lane >> 4);
                bf16x8 afrag = *reinterpret_cast<const bf16x8*>((char*)As + row * 128 + ((g ^ (row & 7)) << 4));
                acc[mo][0] = __builtin_amdgcn_mfma_f32_16x16x32_bf16(afrag, bfrag[kk][0], acc[mo][0], 0, 0, 0);
                acc[mo][1] = __builtin_amdgcn_mfma_f32_16x16x32_bf16(afrag, bfrag[kk][1], acc[mo][1], 0, 0, 0);
            }
        }
        __syncthreads();
    }

    // ---- Yb store ----
#pragma unroll
    for (int mo = 0; mo < 4; ++mo)
#pragma unroll
        for (int no = 0; no < 2; ++no) {
            int col = n0 + wc * 32 + no * 16 + (lane & 15);
            int rbase = m0 + wm * 64 + mo * 16 + (lane >> 4) * 4;
#pragma unroll
            for (int j = 0; j < 4; ++j) {
                int row = rbase + j;
                if (row < N) Yb[(size_t)row * NOUT + col] = f2bf(acc[mo][no][j]);
            }
        }

    // ---- fused score epilogue ----
    float cs0, cs1, cd0, cd1;
    {
        int c0 = n0 + wc * 32 + (lane & 15);
        cs0 = asrc[c0]; cd0 = adst[c0];
        cs1 = asrc[c0 + 16]; cd1 = adst[c0 + 16];
    }
#pragma unroll
    for (int mo = 0; mo < 4; ++mo) {
        float ps[4], pd[4];
#pragma unroll
        for (int j = 0; j < 4; ++j) {
            ps[j] = acc[mo][0][j] * cs0 + acc[mo][1][j] * cs1;
            pd[j] = acc[mo][0][j] * cd0 + acc[mo][1][j] * cd1;
        }
#pragma unroll
        for (int off = 8; off; off >>= 1)
#pragma unroll
            for (int j = 0; j < 4; ++j) {
                ps[j] += __shfl_xor(ps[j], off, 64);
                pd[j] += __shfl_xor(pd[j], off, 64);
            }
        if ((lane & 15) == 0) {
            int rl = wm * 64 + mo * 16 + (lane >> 4) * 4;
#pragma unroll
            for (int j = 0; j < 4; ++j) {
                sred[wc][0][rl + j] = ps[j];
                sred[wc][1][rl + j] = pd[j];
            }
        }
    }
    __syncthreads();
    if (tid < 128) {
        int grow = m0 + tid;
        if (grow < N) {
            float fs = sred[0][0][tid] + sred[1][0][tid];
            float fd = sred[0][1][tid] + sred[1][1][tid];
            if constexpr (C <= 64) {
                int hh = n0 / C;
                ssrc[(size_t)grow * H + hh] = fs;
                sdst[(size_t)grow * H + hh] = fd;
            } else {
                atomicAdd(&ssrc[grow], fs);
                atomicAdd(&sdst[grow], fd);
            }
        }
    }
}

// ---------- fused per-node softmax + bf16 gather-aggregate + epilogue ----------
// One GRP-lane group per node; softmax without max-subtract; unnormalized alpha
// in per-group LDS tables; 1/l folded into epilogue. 4-deep gather (round-10 tuning:
// 8-deep raised VGPR 36->56, occupancy 60->36%, net regression).
template<int H, int C, int GRP, bool ELU, bool OUT_BF16>
__global__ void node_agg_k(const int* __restrict__ rowstart, const int* __restrict__ adj,
                           const float* __restrict__ ssrc, const float* __restrict__ sdst,
                           const unsigned* __restrict__ hb, const float* __restrict__ bias,
                           void* __restrict__ outp, int N) {
    constexpr int HC = H * C;
    constexpr int ROW_U = HC / 2;           // packed uints per row
    constexpr int ULN = ROW_U / GRP;        // uints per lane (=4: 16B)
    constexpr int FPLn = ULN * 2;           // features per lane (=8)
    constexpr int NG = 64 / GRP;            // groups (nodes) per wave
    constexpr int NGB = 4 * NG;             // groups per block (4 waves)
    int lane = threadIdx.x & 63;
    int w = threadIdx.x >> 6;
    int g = lane / GRP, ln = lane % GRP;
    int gid = w * NG + g;
    int n = blockIdx.x * NGB + gid;
    if (n >= N) return;

    __shared__ int   s_tab[NGB][64];
    __shared__ float a_tab[NGB][64 * H];

    int r0 = rowstart[n], r1 = rowstart[n + 1];
    int deg = r1 - r0;

    float sd[H];
#pragma unroll
    for (int h = 0; h < H; ++h) sd[h] = sdst[n * H + h];

    int hA = (ln * FPLn) / C;
    const unsigned* hbl = hb + ln * ULN;
    float acc[FPLn];
#pragma unroll
    for (int f = 0; f < FPLn; ++f) acc[f] = 0.f;
    float l[H];
#pragma unroll
    for (int h = 0; h < H; ++h) l[h] = 0.f;

    if (deg <= 64) {
        // ---- pass 1: strided chunks of GRP edges; fill (s, alpha) tables ----
        for (int base = 0; base < deg; base += GRP) {
            int idx = base + ln;
            bool on = idx < deg;
            int s = adj[r0 + (on ? idx : 0)];
            float v[H];
            if constexpr (H == 4) {
                float4 sv = reinterpret_cast<const float4*>(ssrc)[s];
                v[0] = sv.x; v[1] = sv.y; v[2] = sv.z; v[3] = sv.w;
            } else {
                v[0] = ssrc[s];
            }
#pragma unroll
            for (int h = 0; h < H; ++h) {
                float t = v[h] + sd[h];
                t = t > 0.f ? t : 0.2f * t;
                float av = on ? __expf(t) : 0.f;
                l[h] += av;
                if (on) a_tab[gid][idx * H + h] = av;
            }
            if (on) s_tab[gid][idx] = s;
        }
#pragma unroll
        for (int off = GRP / 2; off; off >>= 1)
#pragma unroll
            for (int h = 0; h < H; ++h) l[h] += __shfl_xor(l[h], off, 64);

        // ---- pass 2: table-driven gather, 4-deep unroll ----
        int j = 0;
        for (; j + 3 < deg; j += 4) {
            int s0 = s_tab[gid][j],     s1 = s_tab[gid][j + 1];
            int s2 = s_tab[gid][j + 2], s3 = s_tab[gid][j + 3];
            float a0 = a_tab[gid][j * H + hA],       a1 = a_tab[gid][(j + 1) * H + hA];
            float a2 = a_tab[gid][(j + 2) * H + hA], a3 = a_tab[gid][(j + 3) * H + hA];
            uint4 u0 = *reinterpret_cast<const uint4*>(hbl + (size_t)s0 * ROW_U);
            uint4 u1 = *reinterpret_cast<const uint4*>(hbl + (size_t)s1 * ROW_U);
            uint4 u2 = *reinterpret_cast<const uint4*>(hbl + (size_t)s2 * ROW_U);
            uint4 u3 = *reinterpret_cast<const uint4*>(hbl + (size_t)s3 * ROW_U);
            acc[0] += a0 * bflo(u0.x); acc[1] += a0 * bfhi(u0.x);
            acc[2] += a0 * bflo(u0.y); acc[3] += a0 * bfhi(u0.y);
            acc[4] += a0 * bflo(u0.z); acc[5] += a0 * bfhi(u0.z);
            acc[6] += a0 * bflo(u0.w); acc[7] += a0 * bfhi(u0.w);
            acc[0] += a1 * bflo(u1.x); acc[1] += a1 * bfhi(u1.x);
            acc[2] += a1 * bflo(u1.y); acc[3] += a1 * bfhi(u1.y);
            acc[4] += a1 * bflo(u1.z); acc[5] += a1 * bfhi(u1.z);
            acc[6] += a1 * bflo(u1.w); acc[7] += a1 * bfhi(u1.w);
            acc[0] += a2 * bflo(u2.x); acc[1] += a2 * bfhi(u2.x);
            acc[2] += a2 * bflo(u2.y); acc[3] += a2 * bfhi(u2.y);
            acc[4] += a2 * bflo(u2.z); acc[5] += a2 * bfhi(u2.z);
            acc[6] += a2 * bflo(u2.w); acc[7] += a2 * bfhi(u2.w);
            acc[0] += a3 * bflo(u3.x); acc[1] += a3 * bfhi(u3.x);
            acc[2] += a3 * bflo(u3.y); acc[3] += a3 * bfhi(u3.y);
            acc[4] += a3 * bflo(u3.z); acc[5] += a3 * bfhi(u3.z);
            acc[6] += a3 * bflo(u3.w); acc[7] += a3 * bfhi(u3.w);
        }
        for (; j < deg; ++j) {
            int sj = s_tab[gid][j];
            float al = a_tab[gid][j * H + hA];
            uint4 u = *reinterpret_cast<const uint4*>(hbl + (size_t)sj * ROW_U);
            acc[0] += al * bflo(u.x); acc[1] += al * bfhi(u.x);
            acc[2] += al * bflo(u.y); acc[3] += al * bfhi(u.y);
            acc[4] += al * bflo(u.z); acc[5] += al * bfhi(u.z);
            acc[6] += al * bflo(u.w); acc[7] += al * bfhi(u.w);
        }
    } else {
        // ---- general path (deg > 64): sum pre-pass, recompute alpha in pass 2 ----
        for (int e = r0 + ln; e < r1; e += GRP) {
            int s = adj[e];
#pragma unroll
            for (int h = 0; h < H; ++h) {
                float t = ssrc[s * H + h] + sd[h];
                t = t > 0.f ? t : 0.2f * t;
                l[h] += __expf(t);
            }
        }
#pragma unroll
        for (int off = GRP / 2; off; off >>= 1)
#pragma unroll
            for (int h = 0; h < H; ++h) l[h] += __shfl_xor(l[h], off, 64);
        float sdh = sd[hA];
        for (int e = r0; e < r1; ++e) {
            int s = adj[e];
            float t = ssrc[s * H + hA] + sdh;
            t = t > 0.f ? t : 0.2f * t;
            float al = __expf(t);
            uint4 u = *reinterpret_cast<const uint4*>(hbl + (size_t)s * ROW_U);
            acc[0] += al * bflo(u.x); acc[1] += al * bfhi(u.x);
            acc[2] += al * bflo(u.y); acc[3] += al * bfhi(u.y);
            acc[4] += al * bflo(u.z); acc[5] += al * bfhi(u.z);
            acc[6] += al * bflo(u.w); acc[7] += al * bfhi(u.w);
        }
    }

    // ---- epilogue: normalize, bias, activation, store ----
    float invl = __builtin_amdgcn_rcpf(l[hA]);
#pragma unroll
    for (int f = 0; f < FPLn; ++f) {
        float v = acc[f] * invl + bias[ln * FPLn + f];
        if (ELU) v = v > 0.f ? v : (__expf(v) - 1.f);
        acc[f] = v;
    }
    if constexpr (OUT_BF16) {
        unsigned* op = (unsigned*)outp + (size_t)n * ROW_U + ln * ULN;
        uint4 u = {packbf(acc[0], acc[1]), packbf(acc[2], acc[3]),
                   packbf(acc[4], acc[5]), packbf(acc[6], acc[7])};
        *reinterpret_cast<uint4*>(op) = u;
    } else {
        float* op = (float*)outp + (size_t)n * HC + ln * FPLn;
        *reinterpret_cast<float4*>(op) = make_float4(acc[0], acc[1], acc[2], acc[3]);
        *reinterpret_cast<float4*>(op + 4) = make_float4(acc[4], acc[5], acc[6], acc[7]);
    }
}

// ---------- launch ----------
extern "C" void kernel_launch(void* const* d_in, const int* in_sizes, int n_in,
                              void* d_out, int out_size, void* d_ws, size_t ws_size,
                              hipStream_t stream) {
    const float* x   = (const float*)d_in[0];
    const int*   ei  = (const int*)d_in[1];
    const float* W1  = (const float*)d_in[2];
    const float* as1 = (const float*)d_in[3];
    const float* ad1 = (const float*)d_in[4];
    const float* b1  = (const float*)d_in[5];
    const float* W2  = (const float*)d_in[6];
    const float* as2 = (const float*)d_in[7];
    const float* ad2 = (const float*)d_in[8];
    const float* b2  = (const float*)d_in[9];
    float* out = (float*)d_out;

    const int N  = in_sizes[0] / 128;   // 50000
    const int E  = in_sizes[1] / 2;     // 800000
    const int ET = E + N;
    const int* src = ei;
    const int* dst = ei + E;

    // workspace (4B units)
    unsigned* ws = (unsigned*)d_ws;
    unsigned* h1b   = ws;                              // N*128
    unsigned* agg1b = h1b   + (size_t)N * 128;         // N*128
    unsigned* h2b   = agg1b + (size_t)N * 128;         // N*64
    unsigned* Wt1   = h2b   + (size_t)N * 64;          // 16384
    unsigned* Wt2   = Wt1   + 16384;                   // 16384
    float*    ssrc1 = (float*)(Wt2 + 16384);           // N*4
    float*    sdst1 = ssrc1 + (size_t)N * 4;           // N*4
    float*    ssrc2 = sdst1 + (size_t)N * 4;           // N
    float*    sdst2 = ssrc2 + N;                       // N
    int*      deg   = (int*)(sdst2 + N);               // N (reused as cursor)
    int*      rowst = deg + N;                         // N+1
    int*      bsums = rowst + N + 1;                   // 64
    int*      adj   = bsums + 64;                      // ET

    const int B = 256;
    auto blocks = [](size_t n, int b) { return (int)((n + b - 1) / b); };
    const int nscan = (N + SCAN_ELEMS - 1) / SCAN_ELEMS;

    // ---- zero ssrc2/sdst2/deg in one shot (contiguous) + fused prep ----
    hipMemsetAsync(ssrc2, 0, (size_t)N * 3 * 4, stream);
    {
        int NW1 = 128 * 256, NW2 = 256 * 128;
        size_t tot = (size_t)NW1 + NW2 + E;
        prep_k<<<blocks(tot, B), B, 0, stream>>>(W1, W2, dst, (unsigned short*)Wt1,
                                                 (unsigned short*)Wt2, deg, NW1, NW2, E);
    }

    // ---- CSR build ----
    scan1_k<<<nscan, SCAN_BLK, 0, stream>>>(deg, rowst, bsums, N);
    scan2_k<<<1, 64, 0, stream>>>(bsums, nscan);
    scan3_init_k<<<blocks(N + 1, B), B, 0, stream>>>(rowst, bsums, adj, deg, N, ET);
    scatter_k<<<blocks(E, B), B, 0, stream>>>(src, dst, E, deg, adj);

    // ---- layer 1 (GEMM with in-staging f32->bf16 + fused scores) ----
    {
        dim3 g((N + 127) / 128, 256 / 64);
        gemm_score_k<128, 256, 4, 64, true><<<g, 256, 0, stream>>>(
            x, (const unsigned*)Wt1, (unsigned short*)h1b, as1, ad1, ssrc1, sdst1, N);
    }
    node_agg_k<4, 64, 32, true, true><<<(N + 7) / 8, 256, 0, stream>>>(rowst, adj, ssrc1, sdst1, h1b, b1, agg1b, N);

    // ---- layer 2 (GEMM + fused scores via atomics) ----
    {
        dim3 g((N + 127) / 128, 128 / 64);
        gemm_score_k<256, 128, 1, 128, false><<<g, 256, 0, stream>>>(
            agg1b, (const unsigned*)Wt2, (unsigned short*)h2b, as2, ad2, ssrc2, sdst2, N);
    }
    node_agg_k<1, 128, 16, false, false><<<(N + 15) / 16, 256, 0, stream>>>(rowst, adj, ssrc2, sdst2, h2b, b2, out, N);
}

// Round 13
// 229.964 us; speedup vs baseline: 1.1533x; 1.0657x over previous
//
#include <hip/hip_runtime.h>
#include <cmath>

typedef __attribute__((ext_vector_type(8))) short bf16x8;
typedef __attribute__((ext_vector_type(4))) float f32x4;

// ---------- bf16 pack/unpack ----------
static __device__ __forceinline__ unsigned short f2bf(float f) {
    unsigned u = __float_as_uint(f);
    unsigned r = (u + 0x7fffu + ((u >> 16) & 1u)) >> 16;   // RNE
    return (unsigned short)r;
}
static __device__ __forceinline__ unsigned packbf(float a, float b) {
    return (unsigned)f2bf(a) | ((unsigned)f2bf(b) << 16);
}
static __device__ __forceinline__ float bflo(unsigned u) { return __uint_as_float(u << 16); }
static __device__ __forceinline__ float bfhi(unsigned u) { return __uint_as_float(u & 0xffff0000u); }

// ---------- fused prep: W1/W2 transpose->bf16, edge count ----------
__global__ void prep_k(const float* __restrict__ W1, const float* __restrict__ W2,
                       const int* __restrict__ dst,
                       unsigned short* __restrict__ Wt1, unsigned short* __restrict__ Wt2,
                       int* __restrict__ deg, int NW1, int NW2, int E) {
    int i = blockIdx.x * blockDim.x + threadIdx.x;
    if (i < NW1) { int nn = i / 128, k = i % 128; Wt1[i] = f2bf(W1[(size_t)k * 256 + nn]); return; }
    i -= NW1;
    if (i < NW2) { int nn = i / 256, k = i % 256; Wt2[i] = f2bf(W2[(size_t)k * 128 + nn]); return; }
    i -= NW2;
    if (i < E) atomicAdd(&deg[dst[i]], 1);
}

#define SCAN_BLK 256
#define SCAN_ELEMS 2048

// scan1: deg[i]+1 (implicit self-loop)
__global__ void scan1_k(const int* __restrict__ deg, int* __restrict__ rowstart,
                        int* __restrict__ bsums, int N) {
    __shared__ int sh[SCAN_BLK];
    int t = threadIdx.x;
    int base = blockIdx.x * SCAN_ELEMS + t * 8;
    int vals[8];
    int sum = 0;
#pragma unroll
    for (int i = 0; i < 8; ++i) {
        int idx = base + i;
        vals[i] = (idx < N) ? (deg[idx] + 1) : 0;
        sum += vals[i];
    }
    sh[t] = sum;
    __syncthreads();
    for (int off = 1; off < SCAN_BLK; off <<= 1) {
        int v = (t >= off) ? sh[t - off] : 0;
        __syncthreads();
        sh[t] += v;
        __syncthreads();
    }
    int run = sh[t] - sum;
    if (t == SCAN_BLK - 1) bsums[blockIdx.x] = sh[t];
#pragma unroll
    for (int i = 0; i < 8; ++i) {
        int idx = base + i;
        if (idx < N) rowstart[idx] = run;
        run += vals[i];
    }
}
// wave-parallel exclusive scan of block sums (nb <= 64)
__global__ void scan2_k(int* __restrict__ bsums, int nb) {
    int lane = threadIdx.x;
    int own = (lane < nb) ? bsums[lane] : 0;
    int v = own;
    for (int off = 1; off < 64; off <<= 1) {
        int t = __shfl_up(v, off, 64);
        if (lane >= off) v += t;
    }
    if (lane < nb) bsums[lane] = v - own;
}
// scan3 + initadj fused
__global__ void scan3_init_k(int* __restrict__ rowstart, const int* __restrict__ bsums,
                             int* __restrict__ adj, int* __restrict__ cursor, int N, int total) {
    int i = blockIdx.x * blockDim.x + threadIdx.x;
    if (i < N) {
        int r = rowstart[i] + bsums[i / SCAN_ELEMS];
        rowstart[i] = r;
        adj[r] = i;          // self-loop first
        cursor[i] = r + 1;
    } else if (i == N) {
        rowstart[N] = total;
    }
}
__global__ void scatter_k(const int* __restrict__ src, const int* __restrict__ dst, int E,
                          int* __restrict__ cursor, int* __restrict__ adj) {
    int e = blockIdx.x * blockDim.x + threadIdx.x;
    if (e >= E) return;
    int pos = atomicAdd(&cursor[dst[e]], 1);
    adj[pos] = src[e];
}

// ---------- MFMA GEMM (BM=128, BN=128) + fused attention scores ----------
// AF32: A matrix is f32 in global (converted to bf16 during LDS staging).
// C<=64: each wave's 64 cols = one head -> direct per-wave score stores.
// C>64 : single column-block (grid.y==1) -> LDS combine, no atomics.
template<int K, int NOUT, int H, int C, bool AF32>
__global__ __launch_bounds__(256) void gemm_score_k(const void* __restrict__ Abv,
                                                    const unsigned* __restrict__ Bt,
                                                    unsigned short* __restrict__ Yb,
                                                    const float* __restrict__ asrc,
                                                    const float* __restrict__ adst,
                                                    float* __restrict__ ssrc,
                                                    float* __restrict__ sdst, int N) {
    __shared__ unsigned short As[128 * 64];
    __shared__ unsigned short Bs[128 * 64];
    __shared__ float sred[2][2][128];   // used only when C>64
    int tid = threadIdx.x;
    int lane = tid & 63, wid = tid >> 6;
    int wm = wid >> 1, wc = wid & 1;
    int m0 = blockIdx.x * 128;
    int n0 = blockIdx.y * 128;

    f32x4 acc[4][4] = {};

    for (int k0 = 0; k0 < K; k0 += 64) {
        // stage A: 128 rows x 64 bf16 -> 1024 granules
#pragma unroll
        for (int p = 0; p < 4; ++p) {
            int gl = p * 256 + tid;
            int row = gl >> 3, g = gl & 7;
            int grow = m0 + row; if (grow >= N) grow = N - 1;
            uint4 v;
            if constexpr (AF32) {
                const float* xp = (const float*)Abv + (size_t)grow * K + k0 + g * 8;
                float4 f0 = *reinterpret_cast<const float4*>(xp);
                float4 f1 = *reinterpret_cast<const float4*>(xp + 4);
                v.x = packbf(f0.x, f0.y); v.y = packbf(f0.z, f0.w);
                v.z = packbf(f1.x, f1.y); v.w = packbf(f1.z, f1.w);
            } else {
                v = *reinterpret_cast<const uint4*>((const unsigned*)Abv + (size_t)grow * (K / 2) + k0 / 2 + g * 4);
            }
            *reinterpret_cast<uint4*>((char*)As + row * 128 + ((g ^ (row & 7)) << 4)) = v;
        }
        // stage B: 128 rows(outcols) x 64 bf16 -> 1024 granules
#pragma unroll
        for (int p = 0; p < 4; ++p) {
            int gl = p * 256 + tid;
            int row = gl >> 3, g = gl & 7;
            uint4 v = *reinterpret_cast<const uint4*>(Bt + (size_t)(n0 + row) * (K / 2) + k0 / 2 + g * 4);
            *reinterpret_cast<uint4*>((char*)Bs + row * 128 + ((g ^ (row & 7)) << 4)) = v;
        }
        __syncthreads();

        bf16x8 bfrag[2][4];
#pragma unroll
        for (int kk = 0; kk < 2; ++kk)
#pragma unroll
            for (int no = 0; no < 4; ++no) {
                int row = wc * 64 + no * 16 + (lane & 15);
                int g = kk * 4 + (lane >> 4);
                bfrag[kk][no] = *reinterpret_cast<const bf16x8*>((char*)Bs + row * 128 + ((g ^ (row & 7)) << 4));
            }
#pragma unroll
        for (int mo = 0; mo < 4; ++mo) {
#pragma unroll
            for (int kk = 0; kk < 2; ++kk) {
                int row = wm * 64 + mo * 16 + (lane & 15);
                int g = kk * 4 + (lane >> 4);
                bf16x8 afrag = *reinterpret_cast<const bf16x8*>((char*)As + row * 128 + ((g ^ (row & 7)) << 4));
#pragma unroll
                for (int no = 0; no < 4; ++no)
                    acc[mo][no] = __builtin_amdgcn_mfma_f32_16x16x32_bf16(afrag, bfrag[kk][no], acc[mo][no], 0, 0, 0);
            }
        }
        __syncthreads();
    }

    // ---- Yb store ----
#pragma unroll
    for (int mo = 0; mo < 4; ++mo)
#pragma unroll
        for (int no = 0; no < 4; ++no) {
            int col = n0 + wc * 64 + no * 16 + (lane & 15);
            int rbase = m0 + wm * 64 + mo * 16 + (lane >> 4) * 4;
#pragma unroll
            for (int j = 0; j < 4; ++j) {
                int row = rbase + j;
                if (row < N) Yb[(size_t)row * NOUT + col] = f2bf(acc[mo][no][j]);
            }
        }

    // ---- fused score epilogue ----
    float cs[4], cd[4];
#pragma unroll
    for (int no = 0; no < 4; ++no) {
        int c0 = n0 + wc * 64 + no * 16 + (lane & 15);
        cs[no] = asrc[c0]; cd[no] = adst[c0];
    }
#pragma unroll
    for (int mo = 0; mo < 4; ++mo) {
        float ps[4], pd[4];
#pragma unroll
        for (int j = 0; j < 4; ++j) {
            ps[j] = 0.f; pd[j] = 0.f;
#pragma unroll
            for (int no = 0; no < 4; ++no) {
                ps[j] += acc[mo][no][j] * cs[no];
                pd[j] += acc[mo][no][j] * cd[no];
            }
        }
#pragma unroll
        for (int off = 8; off; off >>= 1)
#pragma unroll
            for (int j = 0; j < 4; ++j) {
                ps[j] += __shfl_xor(ps[j], off, 64);
                pd[j] += __shfl_xor(pd[j], off, 64);
            }
        if ((lane & 15) == 0) {
            int rl = wm * 64 + mo * 16 + (lane >> 4) * 4;
            if constexpr (C <= 64) {
                // wave's 64 cols == one head: direct store
                int hh = (n0 >> 6) + wc;
#pragma unroll
                for (int j = 0; j < 4; ++j) {
                    int row = m0 + rl + j;
                    if (row < N) {
                        ssrc[(size_t)row * H + hh] = ps[j];
                        sdst[(size_t)row * H + hh] = pd[j];
                    }
                }
            } else {
#pragma unroll
                for (int j = 0; j < 4; ++j) {
                    sred[wc][0][rl + j] = ps[j];
                    sred[wc][1][rl + j] = pd[j];
                }
            }
        }
    }
    if constexpr (C > 64) {
        __syncthreads();
        if (tid < 128) {
            int grow = m0 + tid;
            if (grow < N) {
                ssrc[grow] = sred[0][0][tid] + sred[1][0][tid];
                sdst[grow] = sred[0][1][tid] + sred[1][1][tid];
            }
        }
    }
}

// ---------- fused per-node softmax + bf16 gather-aggregate + epilogue ----------
// One GRP-lane group per node; softmax without max-subtract; unnormalized alpha
// in per-group LDS tables; 1/l folded into epilogue. 4-deep gather (round-10 tuning:
// 8-deep raised VGPR 36->56, occupancy 60->36%, net regression).
template<int H, int C, int GRP, bool ELU, bool OUT_BF16>
__global__ void node_agg_k(const int* __restrict__ rowstart, const int* __restrict__ adj,
                           const float* __restrict__ ssrc, const float* __restrict__ sdst,
                           const unsigned* __restrict__ hb, const float* __restrict__ bias,
                           void* __restrict__ outp, int N) {
    constexpr int HC = H * C;
    constexpr int ROW_U = HC / 2;           // packed uints per row
    constexpr int ULN = ROW_U / GRP;        // uints per lane (=4: 16B)
    constexpr int FPLn = ULN * 2;           // features per lane (=8)
    constexpr int NG = 64 / GRP;            // groups (nodes) per wave
    constexpr int NGB = 4 * NG;             // groups per block (4 waves)
    int lane = threadIdx.x & 63;
    int w = threadIdx.x >> 6;
    int g = lane / GRP, ln = lane % GRP;
    int gid = w * NG + g;
    int n = blockIdx.x * NGB + gid;
    if (n >= N) return;

    __shared__ int   s_tab[NGB][64];
    __shared__ float a_tab[NGB][64 * H];

    int r0 = rowstart[n], r1 = rowstart[n + 1];
    int deg = r1 - r0;

    float sd[H];
#pragma unroll
    for (int h = 0; h < H; ++h) sd[h] = sdst[n * H + h];

    int hA = (ln * FPLn) / C;
    const unsigned* hbl = hb + ln * ULN;
    float acc[FPLn];
#pragma unroll
    for (int f = 0; f < FPLn; ++f) acc[f] = 0.f;
    float l[H];
#pragma unroll
    for (int h = 0; h < H; ++h) l[h] = 0.f;

    if (deg <= 64) {
        // ---- pass 1: strided chunks of GRP edges; fill (s, alpha) tables ----
        for (int base = 0; base < deg; base += GRP) {
            int idx = base + ln;
            bool on = idx < deg;
            int s = adj[r0 + (on ? idx : 0)];
            float v[H];
            if constexpr (H == 4) {
                float4 sv = reinterpret_cast<const float4*>(ssrc)[s];
                v[0] = sv.x; v[1] = sv.y; v[2] = sv.z; v[3] = sv.w;
            } else {
                v[0] = ssrc[s];
            }
#pragma unroll
            for (int h = 0; h < H; ++h) {
                float t = v[h] + sd[h];
                t = t > 0.f ? t : 0.2f * t;
                float av = on ? __expf(t) : 0.f;
                l[h] += av;
                if (on) a_tab[gid][idx * H + h] = av;
            }
            if (on) s_tab[gid][idx] = s;
        }
#pragma unroll
        for (int off = GRP / 2; off; off >>= 1)
#pragma unroll
            for (int h = 0; h < H; ++h) l[h] += __shfl_xor(l[h], off, 64);

        // ---- pass 2: table-driven gather, 4-deep unroll ----
        int j = 0;
        for (; j + 3 < deg; j += 4) {
            int s0 = s_tab[gid][j],     s1 = s_tab[gid][j + 1];
            int s2 = s_tab[gid][j + 2], s3 = s_tab[gid][j + 3];
            float a0 = a_tab[gid][j * H + hA],       a1 = a_tab[gid][(j + 1) * H + hA];
            float a2 = a_tab[gid][(j + 2) * H + hA], a3 = a_tab[gid][(j + 3) * H + hA];
            uint4 u0 = *reinterpret_cast<const uint4*>(hbl + (size_t)s0 * ROW_U);
            uint4 u1 = *reinterpret_cast<const uint4*>(hbl + (size_t)s1 * ROW_U);
            uint4 u2 = *reinterpret_cast<const uint4*>(hbl + (size_t)s2 * ROW_U);
            uint4 u3 = *reinterpret_cast<const uint4*>(hbl + (size_t)s3 * ROW_U);
            acc[0] += a0 * bflo(u0.x); acc[1] += a0 * bfhi(u0.x);
            acc[2] += a0 * bflo(u0.y); acc[3] += a0 * bfhi(u0.y);
            acc[4] += a0 * bflo(u0.z); acc[5] += a0 * bfhi(u0.z);
            acc[6] += a0 * bflo(u0.w); acc[7] += a0 * bfhi(u0.w);
            acc[0] += a1 * bflo(u1.x); acc[1] += a1 * bfhi(u1.x);
            acc[2] += a1 * bflo(u1.y); acc[3] += a1 * bfhi(u1.y);
            acc[4] += a1 * bflo(u1.z); acc[5] += a1 * bfhi(u1.z);
            acc[6] += a1 * bflo(u1.w); acc[7] += a1 * bfhi(u1.w);
            acc[0] += a2 * bflo(u2.x); acc[1] += a2 * bfhi(u2.x);
            acc[2] += a2 * bflo(u2.y); acc[3] += a2 * bfhi(u2.y);
            acc[4] += a2 * bflo(u2.z); acc[5] += a2 * bfhi(u2.z);
            acc[6] += a2 * bflo(u2.w); acc[7] += a2 * bfhi(u2.w);
            acc[0] += a3 * bflo(u3.x); acc[1] += a3 * bfhi(u3.x);
            acc[2] += a3 * bflo(u3.y); acc[3] += a3 * bfhi(u3.y);
            acc[4] += a3 * bflo(u3.z); acc[5] += a3 * bfhi(u3.z);
            acc[6] += a3 * bflo(u3.w); acc[7] += a3 * bfhi(u3.w);
        }
        for (; j < deg; ++j) {
            int sj = s_tab[gid][j];
            float al = a_tab[gid][j * H + hA];
            uint4 u = *reinterpret_cast<const uint4*>(hbl + (size_t)sj * ROW_U);
            acc[0] += al * bflo(u.x); acc[1] += al * bfhi(u.x);
            acc[2] += al * bflo(u.y); acc[3] += al * bfhi(u.y);
            acc[4] += al * bflo(u.z); acc[5] += al * bfhi(u.z);
            acc[6] += al * bflo(u.w); acc[7] += al * bfhi(u.w);
        }
    } else {
        // ---- general path (deg > 64): sum pre-pass, recompute alpha in pass 2 ----
        for (int e = r0 + ln; e < r1; e += GRP) {
            int s = adj[e];
#pragma unroll
            for (int h = 0; h < H; ++h) {
                float t = ssrc[s * H + h] + sd[h];
                t = t > 0.f ? t : 0.2f * t;
                l[h] += __expf(t);
            }
        }
#pragma unroll
        for (int off = GRP / 2; off; off >>= 1)
#pragma unroll
            for (int h = 0; h < H; ++h) l[h] += __shfl_xor(l[h], off, 64);
        float sdh = sd[hA];
        for (int e = r0; e < r1; ++e) {
            int s = adj[e];
            float t = ssrc[s * H + hA] + sdh;
            t = t > 0.f ? t : 0.2f * t;
            float al = __expf(t);
            uint4 u = *reinterpret_cast<const uint4*>(hbl + (size_t)s * ROW_U);
            acc[0] += al * bflo(u.x); acc[1] += al * bfhi(u.x);
            acc[2] += al * bflo(u.y); acc[3] += al * bfhi(u.y);
            acc[4] += al * bflo(u.z); acc[5] += al * bfhi(u.z);
            acc[6] += al * bflo(u.w); acc[7] += al * bfhi(u.w);
        }
    }

    // ---- epilogue: normalize, bias, activation, store ----
    float invl = __builtin_amdgcn_rcpf(l[hA]);
#pragma unroll
    for (int f = 0; f < FPLn; ++f) {
        float v = acc[f] * invl + bias[ln * FPLn + f];
        if (ELU) v = v > 0.f ? v : (__expf(v) - 1.f);
        acc[f] = v;
    }
    if constexpr (OUT_BF16) {
        unsigned* op = (unsigned*)outp + (size_t)n * ROW_U + ln * ULN;
        uint4 u = {packbf(acc[0], acc[1]), packbf(acc[2], acc[3]),
                   packbf(acc[4], acc[5]), packbf(acc[6], acc[7])};
        *reinterpret_cast<uint4*>(op) = u;
    } else {
        float* op = (float*)outp + (size_t)n * HC + ln * FPLn;
        *reinterpret_cast<float4*>(op) = make_float4(acc[0], acc[1], acc[2], acc[3]);
        *reinterpret_cast<float4*>(op + 4) = make_float4(acc[4], acc[5], acc[6], acc[7]);
    }
}

// ---------- launch ----------
extern "C" void kernel_launch(void* const* d_in, const int* in_sizes, int n_in,
                              void* d_out, int out_size, void* d_ws, size_t ws_size,
                              hipStream_t stream) {
    const float* x   = (const float*)d_in[0];
    const int*   ei  = (const int*)d_in[1];
    const float* W1  = (const float*)d_in[2];
    const float* as1 = (const float*)d_in[3];
    const float* ad1 = (const float*)d_in[4];
    const float* b1  = (const float*)d_in[5];
    const float* W2  = (const float*)d_in[6];
    const float* as2 = (const float*)d_in[7];
    const float* ad2 = (const float*)d_in[8];
    const float* b2  = (const float*)d_in[9];
    float* out = (float*)d_out;

    const int N  = in_sizes[0] / 128;   // 50000
    const int E  = in_sizes[1] / 2;     // 800000
    const int ET = E + N;
    const int* src = ei;
    const int* dst = ei + E;

    // workspace (4B units)
    unsigned* ws = (unsigned*)d_ws;
    unsigned* h1b   = ws;                              // N*128
    unsigned* agg1b = h1b   + (size_t)N * 128;         // N*128
    unsigned* h2b   = agg1b + (size_t)N * 128;         // N*64
    unsigned* Wt1   = h2b   + (size_t)N * 64;          // 16384
    unsigned* Wt2   = Wt1   + 16384;                   // 16384
    float*    ssrc1 = (float*)(Wt2 + 16384);           // N*4
    float*    sdst1 = ssrc1 + (size_t)N * 4;           // N*4
    float*    ssrc2 = sdst1 + (size_t)N * 4;           // N
    float*    sdst2 = ssrc2 + N;                       // N
    int*      deg   = (int*)(sdst2 + N);               // N (reused as cursor)
    int*      rowst = deg + N;                         // N+1
    int*      bsums = rowst + N + 1;                   // 64
    int*      adj   = bsums + 64;                      // ET

    const int B = 256;
    auto blocks = [](size_t n, int b) { return (int)((n + b - 1) / b); };
    const int nscan = (N + SCAN_ELEMS - 1) / SCAN_ELEMS;

    // ---- zero deg + fused prep ----
    hipMemsetAsync(deg, 0, (size_t)N * 4, stream);
    {
        int NW1 = 128 * 256, NW2 = 256 * 128;
        size_t tot = (size_t)NW1 + NW2 + E;
        prep_k<<<blocks(tot, B), B, 0, stream>>>(W1, W2, dst, (unsigned short*)Wt1,
                                                 (unsigned short*)Wt2, deg, NW1, NW2, E);
    }

    // ---- CSR build ----
    scan1_k<<<nscan, SCAN_BLK, 0, stream>>>(deg, rowst, bsums, N);
    scan2_k<<<1, 64, 0, stream>>>(bsums, nscan);
    scan3_init_k<<<blocks(N + 1, B), B, 0, stream>>>(rowst, bsums, adj, deg, N, ET);
    scatter_k<<<blocks(E, B), B, 0, stream>>>(src, dst, E, deg, adj);

    // ---- layer 1 (GEMM BN=128, in-staging f32->bf16, direct per-head scores) ----
    {
        dim3 g((N + 127) / 128, 2);
        gemm_score_k<128, 256, 4, 64, true><<<g, 256, 0, stream>>>(
            x, (const unsigned*)Wt1, (unsigned short*)h1b, as1, ad1, ssrc1, sdst1, N);
    }
    node_agg_k<4, 64, 32, true, true><<<(N + 7) / 8, 256, 0, stream>>>(rowst, adj, ssrc1, sdst1, h1b, b1, agg1b, N);

    // ---- layer 2 (GEMM BN=128, single col-block, LDS-combined scores) ----
    {
        dim3 g((N + 127) / 128, 1);
        gemm_score_k<256, 128, 1, 128, false><<<g, 256, 0, stream>>>(
            agg1b, (const unsigned*)Wt2, (unsigned short*)h2b, as2, ad2, ssrc2, sdst2, N);
    }
    node_agg_k<1, 128, 16, false, false><<<(N + 15) / 16, 256, 0, stream>>>(rowst, adj, ssrc2, sdst2, h2b, b2, out, N);
}